// Round 3
// baseline (1402.004 us; speedup 1.0000x reference)
//
#include <hip/hip_runtime.h>
#include <hip/hip_bf16.h>
#include <math.h>

#define R 2048
#define K 20
#define TOPK 100
#define SCORE_TH 0.5f
#define NMS_TH 0.5f

static __device__ __constant__ float IMG_W = 1333.0f;
static __device__ __constant__ float IMG_H = 800.0f;

typedef unsigned long long u64;
typedef unsigned int u32;

// Monotone map: float total order -> unsigned total order (handles negatives/-inf).
__device__ __forceinline__ u32 mapf(float f) {
  u32 b = __float_as_uint(f);
  return (b & 0x80000000u) ? ~b : (b | 0x80000000u);
}
__device__ __forceinline__ float unmapf(u32 u) {
  u32 b = (u & 0x80000000u) ? (u & 0x7FFFFFFFu) : ~u;
  return __uint_as_float(b);
}

// ---------------- prep: clip boxes, finite flags ----------------
__global__ void prep_kernel(const float* __restrict__ boxes,
                            const float* __restrict__ scores,
                            float* __restrict__ bx,
                            int* __restrict__ finite) {
  int r = blockIdx.x * blockDim.x + threadIdx.x;
  if (r >= R) return;
  float x1 = boxes[r * 4 + 0], y1 = boxes[r * 4 + 1];
  float x2 = boxes[r * 4 + 2], y2 = boxes[r * 4 + 3];
  bool fin = isfinite(x1) && isfinite(y1) && isfinite(x2) && isfinite(y2);
  for (int c = 0; c < K + 1; ++c) fin = fin && isfinite(scores[r * (K + 1) + c]);
  bx[r * 4 + 0] = fminf(fmaxf(x1, 0.0f), IMG_W);
  bx[r * 4 + 1] = fminf(fmaxf(y1, 0.0f), IMG_H);
  bx[r * 4 + 2] = fminf(fmaxf(x2, 0.0f), IMG_W);
  bx[r * 4 + 3] = fminf(fmaxf(y2, 0.0f), IMG_H);
  finite[r] = fin ? 1 : 0;
}

// ---------------- nms: one wave per class ----------------
// LDS: 16KB keys + 32KB boxes + 8KB areas + 4KB kept-idx + 2KB keep flags = 62KB
__global__ __launch_bounds__(64) void nms_kernel(const float* __restrict__ scores,
                                                 const float* __restrict__ bx,
                                                 const int* __restrict__ finite,
                                                 u64* __restrict__ keybuf) {
  const int c = blockIdx.x;
  const int lane = threadIdx.x;
  __shared__ u64 skeys[R];
  __shared__ float4 sbox[R];
  __shared__ float sarea[R];
  __shared__ unsigned short kidx[R];
  __shared__ unsigned char keepr[R];

  // Build keys: (mapf(score or -inf if invalid) << 32) | ~r.
  // Demoting invalid rows to -inf preserves the relative order of valid rows,
  // hence the exact keep set of the reference (invalid rows never keep/suppress).
  for (int r = lane; r < R; r += 64) {
    float s = scores[r * (K + 1) + c];
    bool valid = (s > SCORE_TH) && (finite[r] != 0);
    float sv = valid ? s : -INFINITY;
    skeys[r] = ((u64)mapf(sv) << 32) | (u32)(~(u32)r);
    keepr[r] = 0;
  }
  __syncthreads();

  // Bitonic sort descending (total order: score desc, r asc).
  for (int k = 2; k <= R; k <<= 1) {
    for (int j = k >> 1; j > 0; j >>= 1) {
      for (int i = lane; i < R; i += 64) {
        int ixj = i ^ j;
        if (ixj > i) {
          u64 a = skeys[i], b = skeys[ixj];
          bool sw = ((i & k) == 0) ? (a < b) : (a > b);
          if (sw) { skeys[i] = b; skeys[ixj] = a; }
        }
      }
      __syncthreads();
    }
  }

  // Gather clipped boxes/areas in sorted order.
  for (int i = lane; i < R; i += 64) {
    int r = (int)(~(u32)skeys[i]);
    const float4 b = reinterpret_cast<const float4*>(bx)[r];
    sbox[i] = b;
    sarea[i] = (b.z - b.x) * (b.w - b.y);
  }
  __syncthreads();

  // Greedy NMS over the sorted prefix of valid entries.
  int m = 0;  // kept count (wave-uniform)
  for (int i = 0; i < R; ++i) {
    u64 key = skeys[i];
    float s = unmapf((u32)(key >> 32));
    if (!(s > SCORE_TH)) break;  // sorted desc: remainder all invalid
    int r = (int)(~(u32)key);
    float4 b = sbox[i];
    float ai = sarea[i];
    bool sup = false;
    for (int j = lane; j < m; j += 64) {
      int jj = kidx[j];
      float4 kb = sbox[jj];
      float lx = fmaxf(b.x, kb.x), ly = fmaxf(b.y, kb.y);
      float rx = fminf(b.z, kb.z), ry = fminf(b.w, kb.w);
      float w = fmaxf(rx - lx, 0.0f), h = fmaxf(ry - ly, 0.0f);
      float inter = w * h;
      float uni = ai + sarea[jj] - inter;
      if (inter / fmaxf(uni, 1e-9f) > NMS_TH) sup = true;
    }
    bool kept = !__any(sup);  // wave-uniform
    if (kept) {
      if (lane == 0) { kidx[m] = (unsigned short)i; keepr[r] = 1; }
      __syncthreads();  // make kidx[m] visible before next iteration
      m++;
    }
  }
  __syncthreads();

  // Emit masked keys for global top-k: (mapf(kept ? s : -inf) << 32) | ~flat.
  for (int r = lane; r < R; r += 64) {
    float s = scores[r * (K + 1) + c];
    u32 flat = (u32)(c * R + r);
    float sv = keepr[r] ? s : -INFINITY;
    keybuf[flat] = ((u64)mapf(sv) << 32) | (u32)(~flat);
  }
}

// ---------------- chunk: sort n-per-block (1024), emit top-128 ----------------
// in has nin valid entries; entries beyond nin are padded by caller convention:
// we handle padding inside (load 0 for i >= nin), 0 sorts below every real key.
__global__ __launch_bounds__(1024) void chunk_kernel(const u64* __restrict__ in,
                                                     int nin,
                                                     u64* __restrict__ outk) {
  const int t = blockIdx.x;
  const int tid = threadIdx.x;
  const int base = t * 1024;
  __shared__ u64 s[1024];
  int gi = base + tid;
  s[tid] = (gi < nin) ? in[gi] : 0ULL;
  __syncthreads();
  for (int k = 2; k <= 1024; k <<= 1) {
    for (int j = k >> 1; j > 0; j >>= 1) {
      int ixj = tid ^ j;
      if (ixj > tid) {
        u64 a = s[tid], b = s[ixj];
        bool sw = ((tid & k) == 0) ? (a < b) : (a > b);
        if (sw) { s[tid] = b; s[ixj] = a; }
      }
      __syncthreads();
    }
  }
  if (tid < 128) outk[t * 128 + tid] = s[tid];
}

// ---------------- final: sort 640 candidates (pad 1024), write outputs ----------------
__global__ __launch_bounds__(1024) void final_kernel(const u64* __restrict__ cand,
                                                     int nin,
                                                     const float* __restrict__ bx,
                                                     float* __restrict__ out) {
  const int tid = threadIdx.x;
  __shared__ u64 s[1024];
  s[tid] = (tid < nin) ? cand[tid] : 0ULL;
  __syncthreads();
  for (int k = 2; k <= 1024; k <<= 1) {
    for (int j = k >> 1; j > 0; j >>= 1) {
      int ixj = tid ^ j;
      if (ixj > tid) {
        u64 a = s[tid], b = s[ixj];
        bool sw = ((tid & k) == 0) ? (a < b) : (a > b);
        if (sw) { s[tid] = b; s[ixj] = a; }
      }
      __syncthreads();
    }
  }
  if (tid < TOPK) {
    u64 key = s[tid];
    float sc = unmapf((u32)(key >> 32));
    u32 flat = ~(u32)key;
    int c = (int)(flat >> 11);   // / 2048
    int r = (int)(flat & 2047);  // % 2048
    out[tid] = sc;
    out[100 + 4 * tid + 0] = bx[r * 4 + 0];
    out[100 + 4 * tid + 1] = bx[r * 4 + 1];
    out[100 + 4 * tid + 2] = bx[r * 4 + 2];
    out[100 + 4 * tid + 3] = bx[r * 4 + 3];
    out[500 + tid] = (float)c;
    out[600 + tid] = (float)r;
  }
}

extern "C" void kernel_launch(void* const* d_in, const int* in_sizes, int n_in,
                              void* d_out, int out_size, void* d_ws, size_t ws_size,
                              hipStream_t stream) {
  const float* boxes = (const float*)d_in[0];
  const float* scores = (const float*)d_in[1];
  float* out = (float*)d_out;
  char* ws = (char*)d_ws;
  float* bx = (float*)(ws + 0);              // 2048*4*4   = 32768 B
  int* finite = (int*)(ws + 32768);          // 2048*4     =  8192 B
  u64* keybuf = (u64*)(ws + 40960);          // 40960*8    = 327680 B
  u64* cand1 = (u64*)(ws + 368640);          // 40*128*8   = 40960 B
  u64* cand2 = (u64*)(ws + 409600);          // 5*128*8    =  5120 B
  (void)in_sizes; (void)n_in; (void)out_size; (void)ws_size;

  prep_kernel<<<8, 256, 0, stream>>>(boxes, scores, bx, finite);
  nms_kernel<<<K, 64, 0, stream>>>(scores, bx, finite, keybuf);
  chunk_kernel<<<40, 1024, 0, stream>>>(keybuf, K * R, cand1);   // 40960 -> 5120
  chunk_kernel<<<5, 1024, 0, stream>>>(cand1, 5120, cand2);      // 5120 -> 640
  final_kernel<<<1, 1024, 0, stream>>>(cand2, 640, bx, out);
}

// Round 6
// 257.216 us; speedup vs baseline: 5.4507x; 5.4507x over previous
//
#include <hip/hip_runtime.h>
#include <hip/hip_bf16.h>
#include <math.h>

#define R 2048
#define K 20
#define TOPK 100
#define SCORE_TH 0.5f
#define NMS_TH 0.5f
#define IMGW 1333.0f
#define IMGH 800.0f

typedef unsigned long long u64;
typedef unsigned int u32;

#define MAPF_MINF 0x007FFFFFu  // mapf(-inf)
#define MAPF_TH 0xBF000000u    // mapf(0.5f)

// Monotone map: float total order -> unsigned total order.
__device__ __forceinline__ u32 mapf(float f) {
  u32 b = __float_as_uint(f);
  return (b & 0x80000000u) ? ~b : (b | 0x80000000u);
}
__device__ __forceinline__ float unmapf(u32 u) {
  u32 b = (u & 0x80000000u) ? (u & 0x7FFFFFFFu) : ~u;
  return __uint_as_float(b);
}

// ---------------- prep: clip boxes, finite flags ----------------
__global__ void prep_kernel(const float* __restrict__ boxes,
                            const float* __restrict__ scores,
                            float* __restrict__ bx,
                            int* __restrict__ finite) {
  int r = blockIdx.x * blockDim.x + threadIdx.x;
  if (r >= R) return;
  float x1 = boxes[r * 4 + 0], y1 = boxes[r * 4 + 1];
  float x2 = boxes[r * 4 + 2], y2 = boxes[r * 4 + 3];
  bool fin = isfinite(x1) && isfinite(y1) && isfinite(x2) && isfinite(y2);
  for (int c = 0; c < K + 1; ++c) fin = fin && isfinite(scores[r * (K + 1) + c]);
  bx[r * 4 + 0] = fminf(fmaxf(x1, 0.0f), IMGW);
  bx[r * 4 + 1] = fminf(fmaxf(y1, 0.0f), IMGH);
  bx[r * 4 + 2] = fminf(fmaxf(x2, 0.0f), IMGW);
  bx[r * 4 + 3] = fminf(fmaxf(y2, 0.0f), IMGH);
  finite[r] = fin ? 1 : 0;
}

// ---------------- sort: per-class bitonic, 1024 threads ----------------
// Key: (mapf(valid ? s : -inf) << 32) | ~r  -> desc sort == score desc, r asc.
__global__ __launch_bounds__(1024) void sort_kernel(const float* __restrict__ scores,
                                                    const float* __restrict__ bx,
                                                    const int* __restrict__ finite,
                                                    u64* __restrict__ sortedkey,
                                                    float4* __restrict__ sboxs,
                                                    int* __restrict__ nvalid) {
  const int c = blockIdx.x;
  const int tid = threadIdx.x;
  __shared__ u64 sk[R];
  for (int r = tid; r < R; r += 1024) {
    float s = scores[r * (K + 1) + c];
    bool valid = (s > SCORE_TH) && (finite[r] != 0);
    u32 hi = valid ? mapf(s) : MAPF_MINF;
    sk[r] = ((u64)hi << 32) | (u32)(~(u32)r);
  }
  __syncthreads();
  for (int k = 2; k <= R; k <<= 1) {
    for (int j = k >> 1; j > 0; j >>= 1) {
      for (int i = tid; i < R; i += 1024) {
        int ixj = i ^ j;
        if (ixj > i) {
          u64 a = sk[i], b = sk[ixj];
          bool sw = ((i & k) == 0) ? (a < b) : (a > b);
          if (sw) { sk[i] = b; sk[ixj] = a; }
        }
      }
      __syncthreads();
    }
  }
  u64* skg = sortedkey + (size_t)c * R;
  float4* sbg = sboxs + (size_t)c * R;
  for (int i = tid; i < R; i += 1024) {
    u64 key = sk[i];
    skg[i] = key;
    u32 r = ~(u32)key;  // low word is ~r, r < 2048 -> exact
    sbg[i] = reinterpret_cast<const float4*>(bx)[r];
    bool vi = ((u32)(key >> 32)) > MAPF_TH;
    if (i == 0 && !vi) nvalid[c] = 0;
    if (vi) {
      bool vlast = (i == R - 1);
      bool vn = vlast ? false : (((u32)(sk[i + 1] >> 32)) > MAPF_TH);
      if (vlast || !vn) nvalid[c] = i + 1;
    }
  }
}

// ---------------- mask: suppression bit-matrix (sorted-index space) ----------------
// mask[c][i][w] bit b: j = 64w+b, j > i, iou(i,j) > TH.  Rows >= nv never read.
__global__ __launch_bounds__(1024) void mask_kernel(const float4* __restrict__ sboxs,
                                                    const int* __restrict__ nvalid,
                                                    u64* __restrict__ maskbuf) {
  const int c = blockIdx.x;
  const int tid = threadIdx.x;
  const int lane = tid & 63;
  const int wave = tid >> 6;  // 0..15
  __shared__ float4 sb[R];
  __shared__ float sa[R];
  const float4* sbg = sboxs + (size_t)c * R;
  const int nv = nvalid[c];
  for (int i = tid; i < R; i += 1024) {
    float4 b = sbg[i];
    sb[i] = b;
    sa[i] = (b.z - b.x) * (b.w - b.y);
  }
  __syncthreads();
  const int wend = (nv + 63) >> 6;
  u64* mrowbase = maskbuf + (size_t)c * R * 32;
  for (int row = blockIdx.y * 16 + wave; row < nv; row += 128) {
    float4 b = sb[row];
    float ai = sa[row];
    u64 myword = 0;
    int wstart = row >> 6;
    for (int w = wstart; w < wend; ++w) {
      int col = (w << 6) + lane;
      float4 q = sb[col];
      float lx = fmaxf(b.x, q.x), ly = fmaxf(b.y, q.y);
      float rx = fminf(b.z, q.z), ry = fminf(b.w, q.w);
      float ww = fmaxf(rx - lx, 0.0f), hh = fmaxf(ry - ly, 0.0f);
      float inter = ww * hh;
      float uni = ai + sa[col] - inter;
      bool bit = (col > row) && (inter / fmaxf(uni, 1e-9f) > NMS_TH);
      u64 word = __ballot(bit);
      if (lane == w) myword = word;  // lane w keeps word w (w < 32)
    }
    u64* mrow = mrowbase + (size_t)row * 32;
    if (lane < 32) mrow[lane] = myword;  // words outside [wstart,wend) are 0
  }
}

// ---------------- scan: serial greedy resolution via distributed bitmask ----------------
// lane w (<32) owns remv word w. Chain per iter: shfl -> test -> cond-OR.
__global__ __launch_bounds__(64) void scan_kernel(const u64* __restrict__ sortedkey,
                                                  const int* __restrict__ nvalid,
                                                  const u64* __restrict__ maskbuf,
                                                  u64* __restrict__ keybuf) {
  const int c = blockIdx.x;
  const int lane = threadIdx.x;
  const int nv = nvalid[c];
  const u64* mb = maskbuf + (size_t)c * R * 32;
  u64 remv = 0, keepm = 0;
  u64 ring[16];  // static indices only (unrolled) -> stays in VGPRs
#pragma unroll
  for (int s = 0; s < 16; ++s)
    ring[s] = (s < nv && lane < 32) ? mb[(size_t)s * 32 + lane] : 0ULL;
  for (int ib = 0; ib < nv; ib += 16) {
#pragma unroll
    for (int s = 0; s < 16; ++s) {
      int i = ib + s;
      bool act = i < nv;
      int widx = i >> 6;
      int bit = i & 63;
      u64 wv = __shfl(remv, widx, 64);
      bool keep = act && !((wv >> bit) & 1ULL);
      if (keep) {
        remv |= ring[s];
        if (lane == widx) keepm |= (1ULL << bit);
      }
      int ipf = i + 16;  // prefetch 16 ahead into the slot just consumed
      ring[s] = (ipf < nv && lane < 32) ? mb[(size_t)ipf * 32 + lane] : 0ULL;
    }
  }
  __shared__ u64 kw[32];
  if (lane < 32) kw[lane] = keepm;
  __syncthreads();
  // Emit masked keys for global top-k: (mapf(kept ? s : -inf) << 32) | ~flat.
  const u64* skg = sortedkey + (size_t)c * R;
  for (int i = lane; i < R; i += 64) {
    u64 key = skg[i];
    bool kept = (i < nv) && ((kw[i >> 6] >> (i & 63)) & 1ULL);
    u32 r = ~(u32)key;
    u32 flat = (u32)c * R + r;
    u32 hi = kept ? (u32)(key >> 32) : MAPF_MINF;
    keybuf[flat] = ((u64)hi << 32) | (u32)(~flat);
  }
}

// ---------------- fallback nms (round-3, passed at 1402us): one wave per class ----------------
__global__ __launch_bounds__(64) void nms_kernel(const float* __restrict__ scores,
                                                 const float* __restrict__ bx,
                                                 const int* __restrict__ finite,
                                                 u64* __restrict__ keybuf) {
  const int c = blockIdx.x;
  const int lane = threadIdx.x;
  __shared__ u64 skeys[R];
  __shared__ float4 sbox[R];
  __shared__ float sarea[R];
  __shared__ unsigned short kidx[R];
  __shared__ unsigned char keepr[R];
  for (int r = lane; r < R; r += 64) {
    float s = scores[r * (K + 1) + c];
    bool valid = (s > SCORE_TH) && (finite[r] != 0);
    float sv = valid ? s : -INFINITY;
    skeys[r] = ((u64)mapf(sv) << 32) | (u32)(~(u32)r);
    keepr[r] = 0;
  }
  __syncthreads();
  for (int k = 2; k <= R; k <<= 1) {
    for (int j = k >> 1; j > 0; j >>= 1) {
      for (int i = lane; i < R; i += 64) {
        int ixj = i ^ j;
        if (ixj > i) {
          u64 a = skeys[i], b = skeys[ixj];
          bool sw = ((i & k) == 0) ? (a < b) : (a > b);
          if (sw) { skeys[i] = b; skeys[ixj] = a; }
        }
      }
      __syncthreads();
    }
  }
  for (int i = lane; i < R; i += 64) {
    int r = (int)(~(u32)skeys[i]);
    const float4 b = reinterpret_cast<const float4*>(bx)[r];
    sbox[i] = b;
    sarea[i] = (b.z - b.x) * (b.w - b.y);
  }
  __syncthreads();
  int m = 0;
  for (int i = 0; i < R; ++i) {
    u64 key = skeys[i];
    float s = unmapf((u32)(key >> 32));
    if (!(s > SCORE_TH)) break;
    int r = (int)(~(u32)key);
    float4 b = sbox[i];
    float ai = sarea[i];
    bool sup = false;
    for (int j = lane; j < m; j += 64) {
      int jj = kidx[j];
      float4 kb = sbox[jj];
      float lx = fmaxf(b.x, kb.x), ly = fmaxf(b.y, kb.y);
      float rx = fminf(b.z, kb.z), ry = fminf(b.w, kb.w);
      float w = fmaxf(rx - lx, 0.0f), h = fmaxf(ry - ly, 0.0f);
      float inter = w * h;
      float uni = ai + sarea[jj] - inter;
      if (inter / fmaxf(uni, 1e-9f) > NMS_TH) sup = true;
    }
    bool kept = !__any(sup);
    if (kept) {
      if (lane == 0) { kidx[m] = (unsigned short)i; keepr[r] = 1; }
      __syncthreads();
      m++;
    }
  }
  __syncthreads();
  for (int r = lane; r < R; r += 64) {
    float s = scores[r * (K + 1) + c];
    u32 flat = (u32)(c * R + r);
    float sv = keepr[r] ? s : -INFINITY;
    keybuf[flat] = ((u64)mapf(sv) << 32) | (u32)(~flat);
  }
}

// ---------------- chunk: sort 1024/block, emit top-128 ----------------
__global__ __launch_bounds__(1024) void chunk_kernel(const u64* __restrict__ in,
                                                     int nin,
                                                     u64* __restrict__ outk) {
  const int t = blockIdx.x;
  const int tid = threadIdx.x;
  __shared__ u64 s[1024];
  int gi = t * 1024 + tid;
  s[tid] = (gi < nin) ? in[gi] : 0ULL;
  __syncthreads();
  for (int k = 2; k <= 1024; k <<= 1) {
    for (int j = k >> 1; j > 0; j >>= 1) {
      int ixj = tid ^ j;
      if (ixj > tid) {
        u64 a = s[tid], b = s[ixj];
        bool sw = ((tid & k) == 0) ? (a < b) : (a > b);
        if (sw) { s[tid] = b; s[ixj] = a; }
      }
      __syncthreads();
    }
  }
  if (tid < 128) outk[t * 128 + tid] = s[tid];
}

// ---------------- final: sort 640 candidates (pad 1024), write outputs ----------------
__global__ __launch_bounds__(1024) void final_kernel(const u64* __restrict__ cand,
                                                     int nin,
                                                     const float* __restrict__ bx,
                                                     float* __restrict__ out) {
  const int tid = threadIdx.x;
  __shared__ u64 s[1024];
  s[tid] = (tid < nin) ? cand[tid] : 0ULL;
  __syncthreads();
  for (int k = 2; k <= 1024; k <<= 1) {
    for (int j = k >> 1; j > 0; j >>= 1) {
      int ixj = tid ^ j;
      if (ixj > tid) {
        u64 a = s[tid], b = s[ixj];
        bool sw = ((tid & k) == 0) ? (a < b) : (a > b);
        if (sw) { s[tid] = b; s[ixj] = a; }
      }
      __syncthreads();
    }
  }
  if (tid < TOPK) {
    u64 key = s[tid];
    float sc = unmapf((u32)(key >> 32));
    u32 flat = ~(u32)key;
    int c = (int)(flat >> 11);   // / 2048
    int r = (int)(flat & 2047);  // % 2048
    out[tid] = sc;
    out[100 + 4 * tid + 0] = bx[r * 4 + 0];
    out[100 + 4 * tid + 1] = bx[r * 4 + 1];
    out[100 + 4 * tid + 2] = bx[r * 4 + 2];
    out[100 + 4 * tid + 3] = bx[r * 4 + 3];
    out[500 + tid] = (float)c;
    out[600 + tid] = (float)r;
  }
}

extern "C" void kernel_launch(void* const* d_in, const int* in_sizes, int n_in,
                              void* d_out, int out_size, void* d_ws, size_t ws_size,
                              hipStream_t stream) {
  const float* boxes = (const float*)d_in[0];
  const float* scores = (const float*)d_in[1];
  float* out = (float*)d_out;
  char* ws = (char*)d_ws;
  // Common small buffers:
  float* bx = (float*)(ws + 0);                  //     32768 B
  int* finite = (int*)(ws + 32768);              //      8192 B
  (void)in_sizes; (void)n_in; (void)out_size;

  prep_kernel<<<8, 256, 0, stream>>>(boxes, scores, bx, finite);

  if (ws_size >= 11908096) {
    // Bitmask pipeline (needs ~11.9 MB workspace).
    u64* sortedkey = (u64*)(ws + 40960);         //    327680 B (20*2048*8)
    float4* sboxs = (float4*)(ws + 368640);      //    655360 B (20*2048*16)
    int* nvalid = (int*)(ws + 1024000);          //       256 B
    u64* maskbuf = (u64*)(ws + 1048576);         //  10485760 B (20*2048*32*8)
    u64* keybuf = (u64*)(ws + 11534336);         //    327680 B
    u64* cand1 = (u64*)(ws + 11862016);          //     40960 B
    u64* cand2 = (u64*)(ws + 11902976);          //      5120 B
    sort_kernel<<<K, 1024, 0, stream>>>(scores, bx, finite, sortedkey, sboxs, nvalid);
    mask_kernel<<<dim3(K, 8), 1024, 0, stream>>>(sboxs, nvalid, maskbuf);
    scan_kernel<<<K, 64, 0, stream>>>(sortedkey, nvalid, maskbuf, keybuf);
    chunk_kernel<<<40, 1024, 0, stream>>>(keybuf, K * R, cand1);  // 40960 -> 5120
    chunk_kernel<<<5, 1024, 0, stream>>>(cand1, 5120, cand2);     // 5120 -> 640
    final_kernel<<<1, 1024, 0, stream>>>(cand2, 640, bx, out);
  } else {
    // Fallback: round-3 serial pipeline (415 KB workspace), known-correct.
    u64* keybuf = (u64*)(ws + 40960);            //    327680 B
    u64* cand1 = (u64*)(ws + 368640);            //     40960 B
    u64* cand2 = (u64*)(ws + 409600);            //      5120 B
    nms_kernel<<<K, 64, 0, stream>>>(scores, bx, finite, keybuf);
    chunk_kernel<<<40, 1024, 0, stream>>>(keybuf, K * R, cand1);
    chunk_kernel<<<5, 1024, 0, stream>>>(cand1, 5120, cand2);
    final_kernel<<<1, 1024, 0, stream>>>(cand2, 640, bx, out);
  }
}